// Round 1
// baseline (609.692 us; speedup 1.0000x reference)
//
#include <hip/hip_runtime.h>

// GraphNormalization on MI355X.
// x: [N, D=128] f32, seg: [N] sorted int32 in [0, B=1024).
// Per (segment, dim): mean/var over rows; out = (x-mean)/(std+EPS)*gamma+beta,
// pass-through (x*gamma+beta) for segments with cnt<=1.
//
// One 256-thread block per (segment, tensor). 32 lanes * float4 = 128 dims,
// 8 row-groups stream rows. Two passes over the segment's rows (~500 KB),
// memory-bound by design.

static constexpr int   D4  = 32;     // D/4, D = 128 fixed by problem
static constexpr float EPS = 1e-5f;

__global__ __launch_bounds__(256) void seg_norm_kernel(
    const float4* __restrict__ xn, const float4* __restrict__ xe,
    const float*  __restrict__ gn, const float*  __restrict__ bn,
    const float*  __restrict__ ge, const float*  __restrict__ be,
    const int*    __restrict__ sn, const int*    __restrict__ se,
    float4* __restrict__ on, float4* __restrict__ oe,
    int N)
{
    const bool is_edge = (blockIdx.y != 0);
    const float4* __restrict__ x   = is_edge ? xe : xn;
    const float*  __restrict__ gam = is_edge ? ge : gn;
    const float*  __restrict__ bet = is_edge ? be : bn;
    const int*    __restrict__ seg = is_edge ? se : sn;
    float4*       __restrict__ out = is_edge ? oe : on;

    const int b   = (int)blockIdx.x;
    const int tid = (int)threadIdx.x;

    // --- segment bounds via lower_bound on the sorted seg array ---
    __shared__ int s_bounds[2];
    if (tid < 2) {
        const int target = b + tid;
        int lo = 0, hi = N;
        while (lo < hi) {
            int mid = (lo + hi) >> 1;
            if (seg[mid] < target) lo = mid + 1; else hi = mid;
        }
        s_bounds[tid] = lo;
    }
    __syncthreads();
    const int start = s_bounds[0];
    const int end   = s_bounds[1];
    const int cnt   = end - start;
    if (cnt <= 0) return;

    const int lane = tid & 31;   // dim-group: 4 dims per lane
    const int rg   = tid >> 5;   // row-group 0..7

    // --- pass A: accumulate sum and sum-of-squares per dim ---
    float4 s = {0.f, 0.f, 0.f, 0.f};
    float4 q = {0.f, 0.f, 0.f, 0.f};
    for (int r = start + rg; r < end; r += 8) {
        const float4 v = x[(size_t)r * D4 + lane];
        s.x += v.x; s.y += v.y; s.z += v.z; s.w += v.w;
        q.x += v.x * v.x; q.y += v.y * v.y;
        q.z += v.z * v.z; q.w += v.w * v.w;
    }

    __shared__ float4 redS[256];
    __shared__ float4 redQ[256];
    redS[tid] = s;
    redQ[tid] = q;
    __syncthreads();

    // --- reduce 8 row-groups, fold gamma/beta/mean/rstd into scale+bias ---
    if (tid < 32) {
        float4 S = redS[tid];
        float4 Q = redQ[tid];
        #pragma unroll
        for (int k = 1; k < 8; ++k) {
            const float4 a = redS[k * 32 + tid];
            const float4 c = redQ[k * 32 + tid];
            S.x += a.x; S.y += a.y; S.z += a.z; S.w += a.w;
            Q.x += c.x; Q.y += c.y; Q.z += c.z; Q.w += c.w;
        }
        const float rc = 1.0f / (float)cnt;
        float4 m, iv;
        m.x = S.x * rc; m.y = S.y * rc; m.z = S.z * rc; m.w = S.w * rc;
        float vx = fmaxf(Q.x * rc - m.x * m.x, 0.f);
        float vy = fmaxf(Q.y * rc - m.y * m.y, 0.f);
        float vz = fmaxf(Q.z * rc - m.z * m.z, 0.f);
        float vw = fmaxf(Q.w * rc - m.w * m.w, 0.f);
        iv.x = 1.0f / (sqrtf(vx) + EPS);
        iv.y = 1.0f / (sqrtf(vy) + EPS);
        iv.z = 1.0f / (sqrtf(vz) + EPS);
        iv.w = 1.0f / (sqrtf(vw) + EPS);
        if (cnt <= 1) {  // pass-through: out = x*gamma + beta
            m.x = m.y = m.z = m.w = 0.f;
            iv.x = iv.y = iv.z = iv.w = 1.f;
        }
        const float4 g4 = ((const float4*)gam)[tid];
        const float4 b4 = ((const float4*)bet)[tid];
        float4 A, Bc;
        A.x = iv.x * g4.x; A.y = iv.y * g4.y;
        A.z = iv.z * g4.z; A.w = iv.w * g4.w;
        Bc.x = b4.x - m.x * A.x; Bc.y = b4.y - m.y * A.y;
        Bc.z = b4.z - m.z * A.z; Bc.w = b4.w - m.w * A.w;
        redS[tid] = A;   // same-wave lanes only: no race (reads above precede write)
        redQ[tid] = Bc;
    }
    __syncthreads();

    const float4 A  = redS[lane];
    const float4 Bc = redQ[lane];

    // --- pass B: normalize + affine, fully coalesced float4 stream ---
    for (int r = start + rg; r < end; r += 8) {
        const size_t idx = (size_t)r * D4 + lane;
        const float4 v = x[idx];
        float4 o;
        o.x = v.x * A.x + Bc.x;
        o.y = v.y * A.y + Bc.y;
        o.z = v.z * A.z + Bc.z;
        o.w = v.w * A.w + Bc.w;
        out[idx] = o;
    }
}

extern "C" void kernel_launch(void* const* d_in, const int* in_sizes, int n_in,
                              void* d_out, int out_size, void* d_ws, size_t ws_size,
                              hipStream_t stream) {
    const float* node_feat  = (const float*)d_in[0];
    const float* edge_feat  = (const float*)d_in[1];
    const float* node_gamma = (const float*)d_in[2];
    const float* node_beta  = (const float*)d_in[3];
    const float* edge_gamma = (const float*)d_in[4];
    const float* edge_beta  = (const float*)d_in[5];
    const int*   node_seg   = (const int*)d_in[6];
    const int*   edge_seg   = (const int*)d_in[7];
    // d_in[8] = num_graphs scalar on device; B fixed at 1024 by setup_inputs.

    const int D = in_sizes[2];        // 128
    const int N = in_sizes[0] / D;    // 1,000,000
    const int B = 1024;               // num_graphs

    float* out_node = (float*)d_out;
    float* out_edge = out_node + (size_t)N * (size_t)D;

    dim3 grid((unsigned)B, 2);
    seg_norm_kernel<<<grid, 256, 0, stream>>>(
        (const float4*)node_feat, (const float4*)edge_feat,
        node_gamma, node_beta, edge_gamma, edge_beta,
        node_seg, edge_seg,
        (float4*)out_node, (float4*)out_edge, N);
}

// Round 3
// 588.098 us; speedup vs baseline: 1.0367x; 1.0367x over previous
//
#include <hip/hip_runtime.h>

// GraphNormalization on MI355X.
// x: [N, D=128] f32, seg: [N] sorted int32 in [0, B=1024).
// Per (segment, dim): mean/var over rows; out = (x-mean)/(std+EPS)*gamma+beta,
// pass-through (x*gamma+beta) for segments with cnt<=1.
//
// One 256-thread block per (segment, tensor). 32 lanes * float4 = 128 dims,
// 8 row-groups stream rows. Two passes over the segment's rows (~500 KB).
// R1/R2: 4x unrolled streaming loops with batched independent loads (4
// outstanding 16B loads/wave instead of 1) + nontemporal output stores
// (via ext_vector_type alias -- HIP float4 is rejected by the builtin) to
// preserve L2/L3 residency of x for the pass-B re-read.

static constexpr int   D4  = 32;     // D/4, D = 128 fixed by problem
static constexpr float EPS = 1e-5f;

typedef float vfloat4 __attribute__((ext_vector_type(4)));

__device__ __forceinline__ void nt_store4(float4* p, const float4& v) {
    vfloat4 w = { v.x, v.y, v.z, v.w };
    __builtin_nontemporal_store(w, reinterpret_cast<vfloat4*>(p));
}

__global__ __launch_bounds__(256) void seg_norm_kernel(
    const float4* __restrict__ xn, const float4* __restrict__ xe,
    const float*  __restrict__ gn, const float*  __restrict__ bn,
    const float*  __restrict__ ge, const float*  __restrict__ be,
    const int*    __restrict__ sn, const int*    __restrict__ se,
    float4* __restrict__ on, float4* __restrict__ oe,
    int N)
{
    const bool is_edge = (blockIdx.y != 0);
    const float4* __restrict__ x   = is_edge ? xe : xn;
    const float*  __restrict__ gam = is_edge ? ge : gn;
    const float*  __restrict__ bet = is_edge ? be : bn;
    const int*    __restrict__ seg = is_edge ? se : sn;
    float4*       __restrict__ out = is_edge ? oe : on;

    const int b   = (int)blockIdx.x;
    const int tid = (int)threadIdx.x;

    // --- segment bounds via lower_bound on the sorted seg array ---
    __shared__ int s_bounds[2];
    if (tid < 2) {
        const int target = b + tid;
        int lo = 0, hi = N;
        while (lo < hi) {
            int mid = (lo + hi) >> 1;
            if (seg[mid] < target) lo = mid + 1; else hi = mid;
        }
        s_bounds[tid] = lo;
    }
    __syncthreads();
    const int start = s_bounds[0];
    const int end   = s_bounds[1];
    const int cnt   = end - start;
    if (cnt <= 0) return;

    const int lane = tid & 31;   // dim-group: 4 dims per lane
    const int rg   = tid >> 5;   // row-group 0..7

    // --- pass A: accumulate sum and sum-of-squares per dim ---
    float4 s = {0.f, 0.f, 0.f, 0.f};
    float4 q = {0.f, 0.f, 0.f, 0.f};
    {
        int r = start + rg;
        // unroll x4: batch 4 independent loads before consuming
        for (; r + 24 < end; r += 32) {
            const size_t i0 = (size_t)r * D4 + lane;
            const float4 v0 = x[i0];
            const float4 v1 = x[i0 + 8 * D4];
            const float4 v2 = x[i0 + 16 * D4];
            const float4 v3 = x[i0 + 24 * D4];
            s.x += v0.x; s.y += v0.y; s.z += v0.z; s.w += v0.w;
            q.x += v0.x * v0.x; q.y += v0.y * v0.y;
            q.z += v0.z * v0.z; q.w += v0.w * v0.w;
            s.x += v1.x; s.y += v1.y; s.z += v1.z; s.w += v1.w;
            q.x += v1.x * v1.x; q.y += v1.y * v1.y;
            q.z += v1.z * v1.z; q.w += v1.w * v1.w;
            s.x += v2.x; s.y += v2.y; s.z += v2.z; s.w += v2.w;
            q.x += v2.x * v2.x; q.y += v2.y * v2.y;
            q.z += v2.z * v2.z; q.w += v2.w * v2.w;
            s.x += v3.x; s.y += v3.y; s.z += v3.z; s.w += v3.w;
            q.x += v3.x * v3.x; q.y += v3.y * v3.y;
            q.z += v3.z * v3.z; q.w += v3.w * v3.w;
        }
        for (; r < end; r += 8) {
            const float4 v = x[(size_t)r * D4 + lane];
            s.x += v.x; s.y += v.y; s.z += v.z; s.w += v.w;
            q.x += v.x * v.x; q.y += v.y * v.y;
            q.z += v.z * v.z; q.w += v.w * v.w;
        }
    }

    __shared__ float4 redS[256];
    __shared__ float4 redQ[256];
    redS[tid] = s;
    redQ[tid] = q;
    __syncthreads();

    // --- reduce 8 row-groups, fold gamma/beta/mean/rstd into scale+bias ---
    if (tid < 32) {
        float4 S = redS[tid];
        float4 Q = redQ[tid];
        #pragma unroll
        for (int k = 1; k < 8; ++k) {
            const float4 a = redS[k * 32 + tid];
            const float4 c = redQ[k * 32 + tid];
            S.x += a.x; S.y += a.y; S.z += a.z; S.w += a.w;
            Q.x += c.x; Q.y += c.y; Q.z += c.z; Q.w += c.w;
        }
        const float rc = 1.0f / (float)cnt;
        float4 m, iv;
        m.x = S.x * rc; m.y = S.y * rc; m.z = S.z * rc; m.w = S.w * rc;
        float vx = fmaxf(Q.x * rc - m.x * m.x, 0.f);
        float vy = fmaxf(Q.y * rc - m.y * m.y, 0.f);
        float vz = fmaxf(Q.z * rc - m.z * m.z, 0.f);
        float vw = fmaxf(Q.w * rc - m.w * m.w, 0.f);
        iv.x = 1.0f / (sqrtf(vx) + EPS);
        iv.y = 1.0f / (sqrtf(vy) + EPS);
        iv.z = 1.0f / (sqrtf(vz) + EPS);
        iv.w = 1.0f / (sqrtf(vw) + EPS);
        if (cnt <= 1) {  // pass-through: out = x*gamma + beta
            m.x = m.y = m.z = m.w = 0.f;
            iv.x = iv.y = iv.z = iv.w = 1.f;
        }
        const float4 g4 = ((const float4*)gam)[tid];
        const float4 b4 = ((const float4*)bet)[tid];
        float4 A, Bc;
        A.x = iv.x * g4.x; A.y = iv.y * g4.y;
        A.z = iv.z * g4.z; A.w = iv.w * g4.w;
        Bc.x = b4.x - m.x * A.x; Bc.y = b4.y - m.y * A.y;
        Bc.z = b4.z - m.z * A.z; Bc.w = b4.w - m.w * A.w;
        redS[tid] = A;   // same-wave lanes only: no race (reads above precede write)
        redQ[tid] = Bc;
    }
    __syncthreads();

    const float4 A  = redS[lane];
    const float4 Bc = redQ[lane];

    // --- pass B: normalize + affine, coalesced float4 stream, 4x unrolled ---
    {
        int r = start + rg;
        for (; r + 24 < end; r += 32) {
            const size_t i0 = (size_t)r * D4 + lane;
            const float4 v0 = x[i0];
            const float4 v1 = x[i0 + 8 * D4];
            const float4 v2 = x[i0 + 16 * D4];
            const float4 v3 = x[i0 + 24 * D4];
            float4 o0, o1, o2, o3;
            o0.x = v0.x * A.x + Bc.x; o0.y = v0.y * A.y + Bc.y;
            o0.z = v0.z * A.z + Bc.z; o0.w = v0.w * A.w + Bc.w;
            o1.x = v1.x * A.x + Bc.x; o1.y = v1.y * A.y + Bc.y;
            o1.z = v1.z * A.z + Bc.z; o1.w = v1.w * A.w + Bc.w;
            o2.x = v2.x * A.x + Bc.x; o2.y = v2.y * A.y + Bc.y;
            o2.z = v2.z * A.z + Bc.z; o2.w = v2.w * A.w + Bc.w;
            o3.x = v3.x * A.x + Bc.x; o3.y = v3.y * A.y + Bc.y;
            o3.z = v3.z * A.z + Bc.z; o3.w = v3.w * A.w + Bc.w;
            nt_store4(&out[i0],           o0);
            nt_store4(&out[i0 + 8 * D4],  o1);
            nt_store4(&out[i0 + 16 * D4], o2);
            nt_store4(&out[i0 + 24 * D4], o3);
        }
        for (; r < end; r += 8) {
            const size_t idx = (size_t)r * D4 + lane;
            const float4 v = x[idx];
            float4 o;
            o.x = v.x * A.x + Bc.x;
            o.y = v.y * A.y + Bc.y;
            o.z = v.z * A.z + Bc.z;
            o.w = v.w * A.w + Bc.w;
            nt_store4(&out[idx], o);
        }
    }
}

extern "C" void kernel_launch(void* const* d_in, const int* in_sizes, int n_in,
                              void* d_out, int out_size, void* d_ws, size_t ws_size,
                              hipStream_t stream) {
    const float* node_feat  = (const float*)d_in[0];
    const float* edge_feat  = (const float*)d_in[1];
    const float* node_gamma = (const float*)d_in[2];
    const float* node_beta  = (const float*)d_in[3];
    const float* edge_gamma = (const float*)d_in[4];
    const float* edge_beta  = (const float*)d_in[5];
    const int*   node_seg   = (const int*)d_in[6];
    const int*   edge_seg   = (const int*)d_in[7];

    const int D = in_sizes[2];        // 128
    const int N = in_sizes[0] / D;    // 1,000,000
    const int B = 1024;               // num_graphs

    float* out_node = (float*)d_out;
    float* out_edge = out_node + (size_t)N * (size_t)D;

    dim3 grid((unsigned)B, 2);
    seg_norm_kernel<<<grid, 256, 0, stream>>>(
        (const float4*)node_feat, (const float4*)edge_feat,
        node_gamma, node_beta, edge_gamma, edge_beta,
        node_seg, edge_seg,
        (float4*)out_node, (float4*)out_edge, N);
}

// Round 4
// 587.603 us; speedup vs baseline: 1.0376x; 1.0008x over previous
//
#include <hip/hip_runtime.h>

// GraphNormalization on MI355X.
// x: [N, D=128] f32, seg: [N] sorted int32 in [0, B=1024).
// Per (segment, dim): mean/var; out = (x-mean)/(std+EPS)*gamma+beta,
// pass-through (x*gamma+beta) for cnt<=1 segments.
//
// One 256-thread block per (segment, tensor). 32 lanes * float4 = 128 dims,
// 8 row-groups stream rows. Traffic is already minimal (read 1.07 GB from
// HBM in pass A, pass-B re-read is cache-absorbed, write 1.07 GB).
// R3 diagnosis: VGPR_Count=24 proved the compiler serialized the unrolled
// loads (1 outstanding 1KB load/wave -> latency-bound at ~3.2 TB/s).
// R4: 8-deep load batches pinned with sched_barrier(0) so the cluster of
// independent global_load_dwordx4 cannot be re-serialized.

static constexpr int   D4  = 32;     // D/4, D = 128 fixed by problem
static constexpr float EPS = 1e-5f;

typedef float vfloat4 __attribute__((ext_vector_type(4)));

__device__ __forceinline__ void nt_store4(float4* p, const float4& v) {
    vfloat4 w = { v.x, v.y, v.z, v.w };
    __builtin_nontemporal_store(w, reinterpret_cast<vfloat4*>(p));
}

__device__ __forceinline__ void acc4(float4& s, float4& q, const float4& v) {
    s.x += v.x; s.y += v.y; s.z += v.z; s.w += v.w;
    q.x += v.x * v.x; q.y += v.y * v.y;
    q.z += v.z * v.z; q.w += v.w * v.w;
}

__global__ __launch_bounds__(256) void seg_norm_kernel(
    const float4* __restrict__ xn, const float4* __restrict__ xe,
    const float*  __restrict__ gn, const float*  __restrict__ bn,
    const float*  __restrict__ ge, const float*  __restrict__ be,
    const int*    __restrict__ sn, const int*    __restrict__ se,
    float4* __restrict__ on, float4* __restrict__ oe,
    int N)
{
    const bool is_edge = (blockIdx.y != 0);
    const float4* __restrict__ x   = is_edge ? xe : xn;
    const float*  __restrict__ gam = is_edge ? ge : gn;
    const float*  __restrict__ bet = is_edge ? be : bn;
    const int*    __restrict__ seg = is_edge ? se : sn;
    float4*       __restrict__ out = is_edge ? oe : on;

    const int b   = (int)blockIdx.x;
    const int tid = (int)threadIdx.x;

    // --- segment bounds via lower_bound on the sorted seg array ---
    __shared__ int s_bounds[2];
    if (tid < 2) {
        const int target = b + tid;
        int lo = 0, hi = N;
        while (lo < hi) {
            int mid = (lo + hi) >> 1;
            if (seg[mid] < target) lo = mid + 1; else hi = mid;
        }
        s_bounds[tid] = lo;
    }
    __syncthreads();
    const int start = s_bounds[0];
    const int end   = s_bounds[1];
    const int cnt   = end - start;
    if (cnt <= 0) return;

    const int lane = tid & 31;   // dim-group: 4 dims per lane
    const int rg   = tid >> 5;   // row-group 0..7

    // --- pass A: accumulate sum and sum-of-squares per dim ---
    float4 s = {0.f, 0.f, 0.f, 0.f};
    float4 q = {0.f, 0.f, 0.f, 0.f};
    {
        int r = start + rg;
        // 8-deep batched loads; sched_barrier pins the cluster so the
        // compiler cannot re-serialize it to save VGPRs.
        for (; r + 56 < end; r += 64) {
            const size_t i0 = (size_t)r * D4 + lane;
            const float4 v0 = x[i0];
            const float4 v1 = x[i0 +  8 * D4];
            const float4 v2 = x[i0 + 16 * D4];
            const float4 v3 = x[i0 + 24 * D4];
            const float4 v4 = x[i0 + 32 * D4];
            const float4 v5 = x[i0 + 40 * D4];
            const float4 v6 = x[i0 + 48 * D4];
            const float4 v7 = x[i0 + 56 * D4];
            __builtin_amdgcn_sched_barrier(0);
            acc4(s, q, v0); acc4(s, q, v1);
            acc4(s, q, v2); acc4(s, q, v3);
            acc4(s, q, v4); acc4(s, q, v5);
            acc4(s, q, v6); acc4(s, q, v7);
        }
        for (; r < end; r += 8) {
            const float4 v = x[(size_t)r * D4 + lane];
            acc4(s, q, v);
        }
    }

    __shared__ float4 redS[256];
    __shared__ float4 redQ[256];
    redS[tid] = s;
    redQ[tid] = q;
    __syncthreads();

    // --- reduce 8 row-groups, fold gamma/beta/mean/rstd into scale+bias ---
    if (tid < 32) {
        float4 S = redS[tid];
        float4 Q = redQ[tid];
        #pragma unroll
        for (int k = 1; k < 8; ++k) {
            const float4 a = redS[k * 32 + tid];
            const float4 c = redQ[k * 32 + tid];
            S.x += a.x; S.y += a.y; S.z += a.z; S.w += a.w;
            Q.x += c.x; Q.y += c.y; Q.z += c.z; Q.w += c.w;
        }
        const float rc = 1.0f / (float)cnt;
        float4 m, iv;
        m.x = S.x * rc; m.y = S.y * rc; m.z = S.z * rc; m.w = S.w * rc;
        float vx = fmaxf(Q.x * rc - m.x * m.x, 0.f);
        float vy = fmaxf(Q.y * rc - m.y * m.y, 0.f);
        float vz = fmaxf(Q.z * rc - m.z * m.z, 0.f);
        float vw = fmaxf(Q.w * rc - m.w * m.w, 0.f);
        iv.x = 1.0f / (sqrtf(vx) + EPS);
        iv.y = 1.0f / (sqrtf(vy) + EPS);
        iv.z = 1.0f / (sqrtf(vz) + EPS);
        iv.w = 1.0f / (sqrtf(vw) + EPS);
        if (cnt <= 1) {  // pass-through: out = x*gamma + beta
            m.x = m.y = m.z = m.w = 0.f;
            iv.x = iv.y = iv.z = iv.w = 1.f;
        }
        const float4 g4 = ((const float4*)gam)[tid];
        const float4 b4 = ((const float4*)bet)[tid];
        float4 A, Bc;
        A.x = iv.x * g4.x; A.y = iv.y * g4.y;
        A.z = iv.z * g4.z; A.w = iv.w * g4.w;
        Bc.x = b4.x - m.x * A.x; Bc.y = b4.y - m.y * A.y;
        Bc.z = b4.z - m.z * A.z; Bc.w = b4.w - m.w * A.w;
        redS[tid] = A;   // same-wave lanes only: no race
        redQ[tid] = Bc;
    }
    __syncthreads();

    const float4 A  = redS[lane];
    const float4 Bc = redQ[lane];

    // --- pass B: normalize + affine, 8-deep batched loads + NT stores ---
    {
        int r = start + rg;
        for (; r + 56 < end; r += 64) {
            const size_t i0 = (size_t)r * D4 + lane;
            const float4 v0 = x[i0];
            const float4 v1 = x[i0 +  8 * D4];
            const float4 v2 = x[i0 + 16 * D4];
            const float4 v3 = x[i0 + 24 * D4];
            const float4 v4 = x[i0 + 32 * D4];
            const float4 v5 = x[i0 + 40 * D4];
            const float4 v6 = x[i0 + 48 * D4];
            const float4 v7 = x[i0 + 56 * D4];
            __builtin_amdgcn_sched_barrier(0);
            float4 o;
            o.x = v0.x * A.x + Bc.x; o.y = v0.y * A.y + Bc.y;
            o.z = v0.z * A.z + Bc.z; o.w = v0.w * A.w + Bc.w;
            nt_store4(&out[i0], o);
            o.x = v1.x * A.x + Bc.x; o.y = v1.y * A.y + Bc.y;
            o.z = v1.z * A.z + Bc.z; o.w = v1.w * A.w + Bc.w;
            nt_store4(&out[i0 +  8 * D4], o);
            o.x = v2.x * A.x + Bc.x; o.y = v2.y * A.y + Bc.y;
            o.z = v2.z * A.z + Bc.z; o.w = v2.w * A.w + Bc.w;
            nt_store4(&out[i0 + 16 * D4], o);
            o.x = v3.x * A.x + Bc.x; o.y = v3.y * A.y + Bc.y;
            o.z = v3.z * A.z + Bc.z; o.w = v3.w * A.w + Bc.w;
            nt_store4(&out[i0 + 24 * D4], o);
            o.x = v4.x * A.x + Bc.x; o.y = v4.y * A.y + Bc.y;
            o.z = v4.z * A.z + Bc.z; o.w = v4.w * A.w + Bc.w;
            nt_store4(&out[i0 + 32 * D4], o);
            o.x = v5.x * A.x + Bc.x; o.y = v5.y * A.y + Bc.y;
            o.z = v5.z * A.z + Bc.z; o.w = v5.w * A.w + Bc.w;
            nt_store4(&out[i0 + 40 * D4], o);
            o.x = v6.x * A.x + Bc.x; o.y = v6.y * A.y + Bc.y;
            o.z = v6.z * A.z + Bc.z; o.w = v6.w * A.w + Bc.w;
            nt_store4(&out[i0 + 48 * D4], o);
            o.x = v7.x * A.x + Bc.x; o.y = v7.y * A.y + Bc.y;
            o.z = v7.z * A.z + Bc.z; o.w = v7.w * A.w + Bc.w;
            nt_store4(&out[i0 + 56 * D4], o);
        }
        for (; r < end; r += 8) {
            const size_t idx = (size_t)r * D4 + lane;
            const float4 v = x[idx];
            float4 o;
            o.x = v.x * A.x + Bc.x;
            o.y = v.y * A.y + Bc.y;
            o.z = v.z * A.z + Bc.z;
            o.w = v.w * A.w + Bc.w;
            nt_store4(&out[idx], o);
        }
    }
}

extern "C" void kernel_launch(void* const* d_in, const int* in_sizes, int n_in,
                              void* d_out, int out_size, void* d_ws, size_t ws_size,
                              hipStream_t stream) {
    const float* node_feat  = (const float*)d_in[0];
    const float* edge_feat  = (const float*)d_in[1];
    const float* node_gamma = (const float*)d_in[2];
    const float* node_beta  = (const float*)d_in[3];
    const float* edge_gamma = (const float*)d_in[4];
    const float* edge_beta  = (const float*)d_in[5];
    const int*   node_seg   = (const int*)d_in[6];
    const int*   edge_seg   = (const int*)d_in[7];

    const int D = in_sizes[2];        // 128
    const int N = in_sizes[0] / D;    // 1,000,000
    const int B = 1024;               // num_graphs

    float* out_node = (float*)d_out;
    float* out_edge = out_node + (size_t)N * (size_t)D;

    dim3 grid((unsigned)B, 2);
    seg_norm_kernel<<<grid, 256, 0, stream>>>(
        (const float4*)node_feat, (const float4*)edge_feat,
        node_gamma, node_beta, edge_gamma, edge_beta,
        node_seg, edge_seg,
        (float4*)out_node, (float4*)out_edge, N);
}